// Round 7
// baseline (1936.631 us; speedup 1.0000x reference)
//
#include <hip/hip_runtime.h>
#include <hip/hip_bf16.h>

#define B_ 8
#define L_ 48
#define N_ 207
#define D_ 64
#define KH 8
#define T_ 13          // CP = CUT_SIZE + NO_PROXIES
#define CUTS_ 4
#define ND_ (N_ * D_)        // 13248
#define TND_ (T_ * ND_)      // 172224
#define M_ (B_ * T_ * N_)    // 21528 rows for dense layers

__device__ __forceinline__ float sigmoidf_(float x) { return 1.f / (1.f + expf(-x)); }

__global__ void zero_kernel(float* p, int n) {
    int i = blockIdx.x * blockDim.x + threadIdx.x;
    if (i < n) p[i] = 0.f;
}

// ---------------------------------------------------------------- param_gen
__global__ void param_gen_kernel(
    const float* __restrict__ h_time, const float* __restrict__ h_space,
    const float* __restrict__ Ttw, const float* __restrict__ Ttb,
    const float* __restrict__ wg_w1, const float* __restrict__ wg_b1,
    const float* __restrict__ wg_w2, const float* __restrict__ wg_b2,
    const float* __restrict__ wg_w3, const float* __restrict__ wg_b3,
    const float* __restrict__ bg_w1, const float* __restrict__ bg_b1,
    const float* __restrict__ bg_w2, const float* __restrict__ bg_b2,
    const float* __restrict__ bg_w3, const float* __restrict__ bg_b3,
    float* __restrict__ Wg, float* __restrict__ Bg)
{
    int blk = blockIdx.x;                 // g*(B*T) + b*T + c
    int g = blk / (B_ * T_);
    int rem = blk % (B_ * T_);
    int b = rem / T_, c = rem % T_;
    const float* h = (g < 2) ? h_time : h_space;

    __shared__ float mem2[64];
    int tid = threadIdx.x;                // 64 threads

    {
        float s = 0.f;
        for (int l = 0; l < L_; ++l)
            s += tanhf(h[(b * L_ + l) * 64 + tid]) * Ttw[(g * T_ + c) * L_ + l];
        mem2[tid] = tanhf(s + Ttb[g * T_ + c]);
    }
    __syncthreads();

    float m1[32], a[5], ab[5];
    for (int j = 0; j < 32; ++j) {
        float s = wg_b1[g * 32 + j];
        for (int hh = 0; hh < 64; ++hh) s += mem2[hh] * wg_w1[(g * 32 + j) * 64 + hh];
        m1[j] = fmaxf(s, 0.f);
    }
    for (int j = 0; j < 5; ++j) {
        float s = wg_b2[g * 5 + j];
        for (int k2 = 0; k2 < 32; ++k2) s += m1[k2] * wg_w2[(g * 5 + j) * 32 + k2];
        a[j] = fmaxf(s, 0.f);
    }
    for (int j = 0; j < 32; ++j) {
        float s = bg_b1[g * 32 + j];
        for (int hh = 0; hh < 64; ++hh) s += mem2[hh] * bg_w1[(g * 32 + j) * 64 + hh];
        m1[j] = fmaxf(s, 0.f);
    }
    for (int j = 0; j < 5; ++j) {
        float s = bg_b2[g * 5 + j];
        for (int k2 = 0; k2 < 32; ++k2) s += m1[k2] * bg_w2[(g * 5 + j) * 32 + k2];
        ab[j] = fmaxf(s, 0.f);
    }

    float* Wout = Wg + (size_t)blk * 4096;
    for (int k2 = 0; k2 < 64; ++k2) {
        int idx = tid * 64 + k2;   // idx = d*64 + e
        const float* w3 = &wg_w3[((size_t)g * 4096 + idx) * 5];
        Wout[idx] = wg_b3[g * 4096 + idx]
                  + a[0]*w3[0] + a[1]*w3[1] + a[2]*w3[2] + a[3]*w3[3] + a[4]*w3[4];
    }
    {
        const float* w3 = &bg_w3[((size_t)g * 64 + tid) * 5];
        Bg[(size_t)blk * 64 + tid] = bg_b3[g * 64 + tid]
                  + ab[0]*w3[0] + ab[1]*w3[1] + ab[2]*w3[2] + ab[3]*w3[3] + ab[4]*w3[4];
    }
}

// ----------------------------------------------- custom linear on virtual t1
// t1[b,t,n,d] = (t==0) ? proxies[cut,n,d]+out_prev[b,n,d] : x[b,cut_start+t-1,n,d]
// Y[b,t,n,e] = sum_d t1 * W[b,t,d,e] + B[b,t,e]
__global__ void lincustom_t1_kernel(
    const float* __restrict__ x, const float* __restrict__ proxies,
    const float* __restrict__ out_prev,
    const float* __restrict__ W0, const float* __restrict__ Bi0,
    const float* __restrict__ W1, const float* __restrict__ Bi1,
    float* __restrict__ Y0, float* __restrict__ Y1, int cut_start, int cut_idx)
{
    int bt = blockIdx.x;  // b*T + t
    int b = bt / T_, t = bt % T_;
    __shared__ float w0[4096], w1[4096], bb0[64], bb1[64];
    int tid = threadIdx.x;
    for (int i = tid; i < 4096; i += blockDim.x) {
        w0[i] = W0[(size_t)bt * 4096 + i];
        w1[i] = W1[(size_t)bt * 4096 + i];
    }
    if (tid < 64) { bb0[tid] = Bi0[bt * 64 + tid]; bb1[tid] = Bi1[bt * 64 + tid]; }
    __syncthreads();

    const float* xrow_base = (t > 0) ? (x + ((size_t)(b * L_ + cut_start + t - 1) * N_) * D_) : nullptr;
    for (int ne = tid; ne < ND_; ne += blockDim.x) {
        int n = ne / 64, e = ne % 64;
        float s0 = bb0[e], s1 = bb1[e];
        if (t == 0) {
            const float* pp = proxies + (size_t)cut_idx * ND_ + n * 64;
            const float* op = out_prev + (size_t)b * ND_ + n * 64;
            for (int d = 0; d < 64; ++d) {
                float xv = pp[d] + op[d];
                s0 += xv * w0[d * 64 + e];
                s1 += xv * w1[d * 64 + e];
            }
        } else {
            const float* xr = xrow_base + (size_t)n * 64;
            for (int d = 0; d < 64; ++d) {
                float xv = xr[d];
                s0 += xv * w0[d * 64 + e];
                s1 += xv * w1[d * 64 + e];
            }
        }
        Y0[(size_t)bt * ND_ + ne] = s0;
        Y1[(size_t)bt * ND_ + ne] = s1;
    }
}

__global__ void lincustom_kernel(
    const float* __restrict__ X,
    const float* __restrict__ W0, const float* __restrict__ Bi0,
    const float* __restrict__ W1, const float* __restrict__ Bi1,
    float* __restrict__ Y0, float* __restrict__ Y1)
{
    int bt = blockIdx.x;
    __shared__ float w0[4096], w1[4096], bb0[64], bb1[64];
    int tid = threadIdx.x;
    for (int i = tid; i < 4096; i += blockDim.x) {
        w0[i] = W0[(size_t)bt * 4096 + i];
        w1[i] = W1[(size_t)bt * 4096 + i];
    }
    if (tid < 64) { bb0[tid] = Bi0[bt * 64 + tid]; bb1[tid] = Bi1[bt * 64 + tid]; }
    __syncthreads();
    const float* Xbt = X + (size_t)bt * ND_;
    for (int ne = tid; ne < ND_; ne += blockDim.x) {
        int n = ne / 64, e = ne % 64;
        const float* xr = Xbt + (size_t)n * 64;
        float s0 = bb0[e], s1 = bb1[e];
        for (int d = 0; d < 64; ++d) {
            float xv = xr[d];
            s0 += xv * w0[d * 64 + e];
            s1 += xv * w1[d * 64 + e];
        }
        Y0[(size_t)bt * ND_ + ne] = s0;
        Y1[(size_t)bt * ND_ + ne] = s1;
    }
}

// ------------------------------------------------------- temporal attention
__global__ void temporal_att_kernel(
    const float* __restrict__ proxies, const float* __restrict__ out_prev,
    const float* __restrict__ klin, const float* __restrict__ vlin,
    const float* __restrict__ rate, float* __restrict__ xatt, int cut_idx)
{
    int bn = blockIdx.x;
    int b = bn / N_, n = bn % N_;
    int h = threadIdx.x;
    if (h >= KH) return;
    float srate = sigmoidf_(rate[0]);
    const float rs8 = 0.35355339059327373f;  // 1/sqrt(8)

    float q[8];
    for (int j = 0; j < 8; ++j)
        q[j] = proxies[(size_t)cut_idx * ND_ + n * 64 + h * 8 + j]
             + out_prev[(size_t)b * ND_ + n * 64 + h * 8 + j];

    float sa[T_];
    for (int t = 0; t < T_; ++t) {
        const float* kp = klin + ((size_t)(b * T_ + t)) * ND_ + n * 64 + h * 8;
        float s = 0.f;
        for (int j = 0; j < 8; ++j) s += q[j] * kp[j];
        sa[t] = sigmoidf_(s * rs8);
    }
    for (int r = 0; r < T_; ++r) {
        float dec = (float)(T_ - r);
        float p[T_], sum = 0.f;
        for (int t = 0; t < T_; ++t) {
            float sg = sigmoidf_(sa[t] * srate * dec);
            float at = tanhf(sa[t] / (1.f + sg));
            p[t] = expf(at);
            sum += p[t];
        }
        float inv = 1.f / sum;
        float acc[8] = {0,0,0,0,0,0,0,0};
        for (int t = 0; t < T_; ++t) {
            float w = p[t] * inv;
            const float* vp = vlin + ((size_t)(b * T_ + t)) * ND_ + n * 64 + h * 8;
            for (int j = 0; j < 8; ++j) acc[j] += w * vp[j];
        }
        float* op = xatt + ((size_t)(b * T_ + r)) * ND_ + n * 64 + h * 8;
        for (int j = 0; j < 8; ++j) op[j] = acc[j];
    }
}

// ---------------------------------------------------------------- dense 64x64
// Y[m,e] = act( sum_d X[m,d]*W[e,d] + b[e] )   (x @ W.T)
template <int ACT>
__global__ void dense_kernel(const float* __restrict__ X, const float* __restrict__ W,
                             const float* __restrict__ bias, float* __restrict__ Y, int M)
{
    __shared__ float w[4096];   // w[d*64+e] = W[e*64+d]
    __shared__ float bb[64];
    int tid = threadIdx.x;
    for (int i = tid; i < 4096; i += blockDim.x) {
        int e = i >> 6, d = i & 63;
        w[d * 64 + e] = W[i];
    }
    if (tid < 64) bb[tid] = bias[tid];
    __syncthreads();

    int total = M * 64;
    for (int i = blockIdx.x * blockDim.x + tid; i < total; i += gridDim.x * blockDim.x) {
        int e = i & 63;
        int row = i >> 6;
        const float* xr = X + (size_t)row * 64;
        float s = bb[e];
        for (int d = 0; d < 64; ++d) s += xr[d] * w[d * 64 + e];
        if (ACT == 1) s = fmaxf(s, 0.f);
        else if (ACT == 2) s = tanhf(s);
        Y[i] = s;
    }
}

// -------------------------------------------------------- spatial attention
__global__ void spatial_att_kernel(const float* __restrict__ Yq,
                                   const float* __restrict__ Ks, const float* __restrict__ Vs,
                                   float* __restrict__ Out)
{
    int blk = blockIdx.x;  // (b*T + t)*KH + h
    int h = blk % KH;
    int bt = blk / KH;
    __shared__ float kl[N_ * 8], vl[N_ * 8];
    int tid = threadIdx.x;
    for (int i = tid; i < N_ * 8; i += blockDim.x) {
        int m = i / 8, j = i % 8;
        kl[i] = Ks[(size_t)bt * ND_ + m * 64 + h * 8 + j];
        vl[i] = Vs[(size_t)bt * ND_ + m * 64 + h * 8 + j];
    }
    __syncthreads();
    const float rs8 = 0.35355339059327373f;
    for (int n = tid; n < N_; n += blockDim.x) {
        float q[8];
        const float* qp = Yq + (size_t)bt * ND_ + n * 64 + h * 8;
        for (int j = 0; j < 8; ++j) q[j] = qp[j] * rs8;
        float mx = -3.4e38f;
        for (int m = 0; m < N_; ++m) {
            float s = 0.f;
            for (int j = 0; j < 8; ++j) s += q[j] * kl[m * 8 + j];
            mx = fmaxf(mx, s);
        }
        float sum = 0.f;
        float acc[8] = {0,0,0,0,0,0,0,0};
        for (int m = 0; m < N_; ++m) {
            float s = 0.f;
            for (int j = 0; j < 8; ++j) s += q[j] * kl[m * 8 + j];
            float p = expf(s - mx);
            sum += p;
            for (int j = 0; j < 8; ++j) acc[j] += p * vl[m * 8 + j];
        }
        float inv = 1.f / sum;
        float* op = Out + (size_t)bt * ND_ + n * 64 + h * 8;
        for (int j = 0; j < 8; ++j) op[j] = acc[j] * inv;
    }
}

// ------------------------------------------------------------- gate + reduce
// OUTPUT IS FLOAT32 (reference computes in fp32; harness reads float*)
__global__ void gate_reduce_kernel(const float* __restrict__ O, const float* __restrict__ G2,
                                   float* __restrict__ out_fp32, float* __restrict__ d_out,
                                   int cut_idx)
{
    int i = blockIdx.x * blockDim.x + threadIdx.x;
    if (i >= B_ * ND_) return;
    int b = i / ND_;
    int nd = i % ND_;
    float s = 0.f;
    for (int t = 0; t < T_; ++t) {
        float o = O[((size_t)(b * T_ + t)) * ND_ + nd];
        float g = G2[((size_t)(b * T_ + t)) * ND_ + nd];
        s += o * sigmoidf_(g);
    }
    out_fp32[i] = s;
    d_out[((size_t)b * CUTS_ + cut_idx) * ND_ + nd] = s;
}

// ======================================================================
extern "C" void kernel_launch(void* const* d_in, const int* in_sizes, int n_in,
                              void* d_out, int out_size, void* d_ws, size_t ws_size,
                              hipStream_t stream)
{
    const float* x        = (const float*)d_in[0];
    const float* h_time   = (const float*)d_in[1];
    const float* h_space  = (const float*)d_in[2];
    const float* gen_Tt_w = (const float*)d_in[3];
    const float* gen_Tt_b = (const float*)d_in[4];
    const float* wg_w1    = (const float*)d_in[5];
    const float* wg_b1    = (const float*)d_in[6];
    const float* wg_w2    = (const float*)d_in[7];
    const float* wg_b2    = (const float*)d_in[8];
    const float* wg_w3    = (const float*)d_in[9];
    const float* wg_b3    = (const float*)d_in[10];
    const float* bg_w1    = (const float*)d_in[11];
    const float* bg_b1    = (const float*)d_in[12];
    const float* bg_w2    = (const float*)d_in[13];
    const float* bg_b2    = (const float*)d_in[14];
    const float* bg_w3    = (const float*)d_in[15];
    const float* bg_b3    = (const float*)d_in[16];
    const float* proxies  = (const float*)d_in[17];
    const float* ta_p1_w  = (const float*)d_in[18];
    const float* ta_p1_b  = (const float*)d_in[19];
    const float* ta_p2_w  = (const float*)d_in[20];
    const float* ta_p2_b  = (const float*)d_in[21];
    const float* rate     = (const float*)d_in[22];
    const float* sa_p1_w  = (const float*)d_in[23];
    const float* sa_p1_b  = (const float*)d_in[24];
    const float* sa_p2_w  = (const float*)d_in[25];
    const float* sa_p2_b  = (const float*)d_in[26];
    const float* agg_w1   = (const float*)d_in[27];
    const float* agg_b1   = (const float*)d_in[28];
    const float* agg_w2   = (const float*)d_in[29];
    const float* agg_b2   = (const float*)d_in[30];

    float* outp = (float*)d_out;

    float* ws = (float*)d_ws;
    const size_t S = (size_t)B_ * TND_;             // 1,378,944 floats
    const size_t genW = (size_t)B_ * T_ * 4096;
    const size_t genB = (size_t)B_ * T_ * 64;
    size_t off = 0;
    float* Wg   = ws + off; off += 4 * genW;
    float* Bg   = ws + off; off += 4 * genB;
    float* A    = ws + off; off += S;
    float* Bb   = ws + off; off += S;
    float* C    = ws + off; off += S;
    float* Dd   = ws + off; off += S;
    float* out_fp32 = ws + off; off += (size_t)B_ * ND_;

    zero_kernel<<<(B_ * ND_ + 255) / 256, 256, 0, stream>>>(out_fp32, B_ * ND_);

    param_gen_kernel<<<4 * B_ * T_, 64, 0, stream>>>(
        h_time, h_space, gen_Tt_w, gen_Tt_b,
        wg_w1, wg_b1, wg_w2, wg_b2, wg_w3, wg_b3,
        bg_w1, bg_b1, bg_w2, bg_b2, bg_w3, bg_b3, Wg, Bg);

    const int cut_starts[4] = {0, 12, 24, 36};
    const int denseGrid = 2048;

    for (int cut = 0; cut < CUTS_; ++cut) {
        // temporal k (gen0) -> A, v (gen1) -> Bb, from virtual t1
        lincustom_t1_kernel<<<B_ * T_, 256, 0, stream>>>(
            x, proxies, out_fp32,
            Wg + 0 * genW, Bg + 0 * genB, Wg + 1 * genW, Bg + 1 * genB,
            A, Bb, cut_starts[cut], cut);
        // temporal attention -> C
        temporal_att_kernel<<<B_ * N_, 64, 0, stream>>>(
            proxies, out_fp32, A, Bb, rate, C, cut);
        // y = dense(tanh(dense(xatt, p1)), p2): tanh-dense -> Dd, dense -> C
        dense_kernel<2><<<denseGrid, 256, 0, stream>>>(C, ta_p1_w, ta_p1_b, Dd, M_);
        dense_kernel<0><<<denseGrid, 256, 0, stream>>>(Dd, ta_p2_w, ta_p2_b, C, M_);
        // spatial k (gen2) -> A, v (gen3) -> Bb
        lincustom_kernel<<<B_ * T_, 256, 0, stream>>>(
            C, Wg + 2 * genW, Bg + 2 * genB, Wg + 3 * genW, Bg + 3 * genB, A, Bb);
        // spatial attention (q = C) -> Dd
        spatial_att_kernel<<<B_ * T_ * KH, 256, 0, stream>>>(C, A, Bb, Dd);
        // o = dense(relu(dense(sa_out, p1)), p2): relu-dense -> A, dense -> Bb
        dense_kernel<1><<<denseGrid, 256, 0, stream>>>(Dd, sa_p1_w, sa_p1_b, A, M_);
        dense_kernel<0><<<denseGrid, 256, 0, stream>>>(A, sa_p2_w, sa_p2_b, Bb, M_);
        // gate: relu-dense -> A, dense -> Dd; then reduce (o = Bb)
        dense_kernel<1><<<denseGrid, 256, 0, stream>>>(Bb, agg_w1, agg_b1, A, M_);
        dense_kernel<0><<<denseGrid, 256, 0, stream>>>(A, agg_w2, agg_b2, Dd, M_);
        gate_reduce_kernel<<<(B_ * ND_ + 255) / 256, 256, 0, stream>>>(
            Bb, Dd, out_fp32, outp, cut);
    }
}

// Round 8
// 1831.749 us; speedup vs baseline: 1.0573x; 1.0573x over previous
//
#include <hip/hip_runtime.h>
#include <hip/hip_bf16.h>

#define B_ 8
#define L_ 48
#define N_ 207
#define D_ 64
#define KH 8
#define T_ 13          // CP = CUT_SIZE + NO_PROXIES
#define CUTS_ 4
#define ND_ (N_ * D_)        // 13248
#define TND_ (T_ * ND_)      // 172224
#define M_ (B_ * T_ * N_)    // 21528 rows for dense layers
#define GBT_ (4 * B_ * T_)   // 416 generator instances

__device__ __forceinline__ float sigmoidf_(float x) { return 1.f / (1.f + expf(-x)); }

__global__ void zero_kernel(float* p, int n) {
    int i = blockIdx.x * blockDim.x + threadIdx.x;
    if (i < n) p[i] = 0.f;
}

// ------------------------------------------------- param_gen stage 1: coefs
// One 64-thread block per (g,b,c). Lane-parallel mem2; lanes 0-31 compute the
// W-generator hidden layer, lanes 32-63 the b-generator. Coef[blk][0..4]=a,
// [8..12]=ab.
__global__ void param_coef_kernel(
    const float* __restrict__ h_time, const float* __restrict__ h_space,
    const float* __restrict__ Ttw, const float* __restrict__ Ttb,
    const float* __restrict__ wg_w1, const float* __restrict__ wg_b1,
    const float* __restrict__ wg_w2, const float* __restrict__ wg_b2,
    const float* __restrict__ bg_w1, const float* __restrict__ bg_b1,
    const float* __restrict__ bg_w2, const float* __restrict__ bg_b2,
    float* __restrict__ Coef)
{
    int blk = blockIdx.x;                 // g*(B*T) + b*T + c
    int g = blk / (B_ * T_);
    int rem = blk % (B_ * T_);
    int b = rem / T_, c = rem % T_;
    const float* h = (g < 2) ? h_time : h_space;
    int lane = threadIdx.x;

    __shared__ float mem2[64];
    __shared__ float m1s[64];

    {
        float s = 0.f;
        for (int l = 0; l < L_; ++l)
            s += tanhf(h[(b * L_ + l) * 64 + lane]) * Ttw[(g * T_ + c) * L_ + l];
        mem2[lane] = tanhf(s + Ttb[g * T_ + c]);
    }
    __syncthreads();
    {
        int j = lane & 31;
        bool isW = lane < 32;
        const float* w1 = isW ? wg_w1 : bg_w1;
        const float* b1 = isW ? wg_b1 : bg_b1;
        float s = b1[g * 32 + j];
        #pragma unroll 8
        for (int hh = 0; hh < 64; ++hh) s += mem2[hh] * w1[(g * 32 + j) * 64 + hh];
        m1s[lane] = fmaxf(s, 0.f);
    }
    __syncthreads();
    if (lane < 5 || (lane >= 8 && lane < 13)) {
        bool isW = lane < 5;
        int j = isW ? lane : lane - 8;
        const float* w2 = isW ? wg_w2 : bg_w2;
        const float* b2 = isW ? wg_b2 : bg_b2;
        int base = isW ? 0 : 32;
        float s = b2[g * 5 + j];
        #pragma unroll
        for (int k = 0; k < 32; ++k) s += m1s[base + k] * w2[(g * 5 + j) * 32 + k];
        Coef[blk * 16 + (isW ? j : 8 + j)] = fmaxf(s, 0.f);
    }
}

// ------------------------------------- param_gen stage 2: materialize W / B
#define WTOT (GBT_ * 4096)      // 1,703,936
#define BTOT (GBT_ * 64)        // 26,624
__global__ void param_mat_kernel(
    const float* __restrict__ wg_w3, const float* __restrict__ wg_b3,
    const float* __restrict__ bg_w3, const float* __restrict__ bg_b3,
    const float* __restrict__ Coef,
    float* __restrict__ Wg, float* __restrict__ Bg)
{
    int i = blockIdx.x * blockDim.x + threadIdx.x;
    if (i < WTOT) {
        int idx = i & 4095;              // = d*64+e
        int blk = i >> 12;
        int g = blk / (B_ * T_);
        const float* w3 = &wg_w3[((size_t)g * 4096 + idx) * 5];
        const float* cf = &Coef[blk * 16];
        Wg[i] = wg_b3[g * 4096 + idx]
              + cf[0]*w3[0] + cf[1]*w3[1] + cf[2]*w3[2] + cf[3]*w3[3] + cf[4]*w3[4];
    } else if (i < WTOT + BTOT) {
        int k = i - WTOT;
        int idx = k & 63;
        int blk = k >> 6;
        int g = blk / (B_ * T_);
        const float* w3 = &bg_w3[((size_t)g * 64 + idx) * 5];
        const float* cf = &Coef[blk * 16];
        Bg[k] = bg_b3[g * 64 + idx]
              + cf[8]*w3[0] + cf[9]*w3[1] + cf[10]*w3[2] + cf[11]*w3[3] + cf[12]*w3[4];
    }
}

// ----------------------------------------------- custom linear (widened)
// grid (B*T, NCHUNK, 2). z=0: W0->Y0, z=1: W1->Y1. Virtual t1 input.
#define NCHUNK 8
#define NROWS 26   // ceil(207/8)
__global__ void lincustom_t1_kernel(
    const float* __restrict__ x, const float* __restrict__ proxies,
    const float* __restrict__ out_prev,
    const float* __restrict__ W0, const float* __restrict__ Bi0,
    const float* __restrict__ W1, const float* __restrict__ Bi1,
    float* __restrict__ Y0, float* __restrict__ Y1, int cut_start, int cut_idx)
{
    int bt = blockIdx.x;  // b*T + t
    int b = bt / T_, t = bt % T_;
    int which = blockIdx.z;
    const float* W  = which ? W1 : W0;
    const float* Bi = which ? Bi1 : Bi0;
    float* Y        = which ? Y1 : Y0;

    __shared__ float w[4096], bb[64];
    int tid = threadIdx.x;
    for (int i = tid; i < 4096; i += blockDim.x)
        w[i] = W[(size_t)bt * 4096 + i];
    if (tid < 64) bb[tid] = Bi[bt * 64 + tid];
    __syncthreads();

    int n0 = blockIdx.y * NROWS;
    int n1 = min(n0 + NROWS, N_);
    const float* xrow_base = (t > 0) ? (x + ((size_t)(b * L_ + cut_start + t - 1) * N_) * D_) : nullptr;
    for (int ne = n0 * 64 + tid; ne < n1 * 64; ne += blockDim.x) {
        int n = ne >> 6, e = ne & 63;
        float s = bb[e];
        if (t == 0) {
            const float* pp = proxies + (size_t)cut_idx * ND_ + n * 64;
            const float* op = out_prev + (size_t)b * ND_ + n * 64;
            #pragma unroll 8
            for (int d = 0; d < 64; ++d) s += (pp[d] + op[d]) * w[d * 64 + e];
        } else {
            const float* xr = xrow_base + (size_t)n * 64;
            #pragma unroll 8
            for (int d = 0; d < 64; ++d) s += xr[d] * w[d * 64 + e];
        }
        Y[(size_t)bt * ND_ + ne] = s;
    }
}

__global__ void lincustom_kernel(
    const float* __restrict__ X,
    const float* __restrict__ W0, const float* __restrict__ Bi0,
    const float* __restrict__ W1, const float* __restrict__ Bi1,
    float* __restrict__ Y0, float* __restrict__ Y1)
{
    int bt = blockIdx.x;
    int which = blockIdx.z;
    const float* W  = which ? W1 : W0;
    const float* Bi = which ? Bi1 : Bi0;
    float* Y        = which ? Y1 : Y0;

    __shared__ float w[4096], bb[64];
    int tid = threadIdx.x;
    for (int i = tid; i < 4096; i += blockDim.x)
        w[i] = W[(size_t)bt * 4096 + i];
    if (tid < 64) bb[tid] = Bi[bt * 64 + tid];
    __syncthreads();

    int n0 = blockIdx.y * NROWS;
    int n1 = min(n0 + NROWS, N_);
    const float* Xbt = X + (size_t)bt * ND_;
    for (int ne = n0 * 64 + tid; ne < n1 * 64; ne += blockDim.x) {
        int n = ne >> 6, e = ne & 63;
        const float* xr = Xbt + (size_t)n * 64;
        float s = bb[e];
        #pragma unroll 8
        for (int d = 0; d < 64; ++d) s += xr[d] * w[d * 64 + e];
        Y[(size_t)bt * ND_ + ne] = s;
    }
}

// ------------------------------------------------------- temporal attention
// One thread per (b,n,h,r): computes output row r for head h of token n.
__global__ void temporal_att_kernel(
    const float* __restrict__ proxies, const float* __restrict__ out_prev,
    const float* __restrict__ klin, const float* __restrict__ vlin,
    const float* __restrict__ rate, float* __restrict__ xatt, int cut_idx)
{
    int i = blockIdx.x * blockDim.x + threadIdx.x;
    if (i >= B_ * N_ * KH * T_) return;
    int r = i % T_;
    int h = (i / T_) % KH;
    int n = (i / (T_ * KH)) % N_;
    int b = i / (T_ * KH * N_);

    float srate = sigmoidf_(rate[0]);
    const float rs8 = 0.35355339059327373f;  // 1/sqrt(8)

    float q[8];
    #pragma unroll
    for (int j = 0; j < 8; ++j)
        q[j] = proxies[(size_t)cut_idx * ND_ + n * 64 + h * 8 + j]
             + out_prev[(size_t)b * ND_ + n * 64 + h * 8 + j];

    float dec = (float)(T_ - r);
    float p[T_], sum = 0.f;
    for (int t = 0; t < T_; ++t) {
        const float* kp = klin + ((size_t)(b * T_ + t)) * ND_ + n * 64 + h * 8;
        float s = 0.f;
        #pragma unroll
        for (int j = 0; j < 8; ++j) s += q[j] * kp[j];
        float sa = sigmoidf_(s * rs8);
        float sg = sigmoidf_(sa * srate * dec);
        float at = tanhf(sa / (1.f + sg));
        p[t] = expf(at);
        sum += p[t];
    }
    float inv = 1.f / sum;
    float acc[8] = {0,0,0,0,0,0,0,0};
    for (int t = 0; t < T_; ++t) {
        float w = p[t] * inv;
        const float* vp = vlin + ((size_t)(b * T_ + t)) * ND_ + n * 64 + h * 8;
        #pragma unroll
        for (int j = 0; j < 8; ++j) acc[j] += w * vp[j];
    }
    float* op = xatt + ((size_t)(b * T_ + r)) * ND_ + n * 64 + h * 8;
    #pragma unroll
    for (int j = 0; j < 8; ++j) op[j] = acc[j];
}

// ------------------------------------------------------ fused dense-dense
// Y = dense(act1(dense(X,W1,b1)), W2,b2). One wave per row (rloc=wave id).
template <int ACT1>
__global__ void dense2_kernel(const float* __restrict__ X,
                              const float* __restrict__ W1, const float* __restrict__ b1,
                              const float* __restrict__ W2, const float* __restrict__ b2,
                              float* __restrict__ Y, int M)
{
    __shared__ float w1[4096], w2[4096];   // transposed: w[d*64+e] = W[e*64+d]
    __shared__ float bb1[64], bb2[64];
    __shared__ float inter[4][64];
    int tid = threadIdx.x;
    for (int i = tid; i < 4096; i += blockDim.x) {
        int e = i >> 6, d = i & 63;
        w1[d * 64 + e] = W1[i];
        w2[d * 64 + e] = W2[i];
    }
    if (tid < 64) { bb1[tid] = b1[tid]; bb2[tid] = b2[tid]; }
    __syncthreads();

    int rloc = tid >> 6;       // 0..3 (= wave id)
    int e = tid & 63;
    int row = blockIdx.x * 4 + rloc;
    float s = bb1[e];
    if (row < M) {
        const float* xr = X + (size_t)row * 64;
        #pragma unroll 8
        for (int d = 0; d < 64; ++d) s += xr[d] * w1[d * 64 + e];
        if (ACT1 == 1) s = fmaxf(s, 0.f);
        else if (ACT1 == 2) s = tanhf(s);
    }
    inter[rloc][e] = s;
    __syncthreads();
    if (row < M) {
        float o = bb2[e];
        #pragma unroll 8
        for (int d = 0; d < 64; ++d) o += inter[rloc][d] * w2[d * 64 + e];
        Y[(size_t)row * 64 + e] = o;
    }
}

// -------------------------------------------------------- spatial attention
__global__ void spatial_att_kernel(const float* __restrict__ Yq,
                                   const float* __restrict__ Ks, const float* __restrict__ Vs,
                                   float* __restrict__ Out)
{
    int blk = blockIdx.x;  // (b*T + t)*KH + h
    int h = blk % KH;
    int bt = blk / KH;
    __shared__ float kl[N_ * 8], vl[N_ * 8];
    int tid = threadIdx.x;
    for (int i = tid; i < N_ * 8; i += blockDim.x) {
        int m = i / 8, j = i % 8;
        kl[i] = Ks[(size_t)bt * ND_ + m * 64 + h * 8 + j];
        vl[i] = Vs[(size_t)bt * ND_ + m * 64 + h * 8 + j];
    }
    __syncthreads();
    const float rs8 = 0.35355339059327373f;
    for (int n = tid; n < N_; n += blockDim.x) {
        float q[8];
        const float* qp = Yq + (size_t)bt * ND_ + n * 64 + h * 8;
        #pragma unroll
        for (int j = 0; j < 8; ++j) q[j] = qp[j] * rs8;
        float mx = -3.4e38f;
        for (int m = 0; m < N_; ++m) {
            float s = 0.f;
            #pragma unroll
            for (int j = 0; j < 8; ++j) s += q[j] * kl[m * 8 + j];
            mx = fmaxf(mx, s);
        }
        float sum = 0.f;
        float acc[8] = {0,0,0,0,0,0,0,0};
        for (int m = 0; m < N_; ++m) {
            float s = 0.f;
            #pragma unroll
            for (int j = 0; j < 8; ++j) s += q[j] * kl[m * 8 + j];
            float p = expf(s - mx);
            sum += p;
            #pragma unroll
            for (int j = 0; j < 8; ++j) acc[j] += p * vl[m * 8 + j];
        }
        float inv = 1.f / sum;
        float* op = Out + (size_t)bt * ND_ + n * 64 + h * 8;
        #pragma unroll
        for (int j = 0; j < 8; ++j) op[j] = acc[j] * inv;
    }
}

// ------------------------------------------------------------- gate + reduce
__global__ void gate_reduce_kernel(const float* __restrict__ O, const float* __restrict__ G2,
                                   float* __restrict__ out_fp32, float* __restrict__ d_out,
                                   int cut_idx)
{
    int i = blockIdx.x * blockDim.x + threadIdx.x;
    if (i >= B_ * ND_) return;
    int b = i / ND_;
    int nd = i % ND_;
    float s = 0.f;
    for (int t = 0; t < T_; ++t) {
        float o = O[((size_t)(b * T_ + t)) * ND_ + nd];
        float g = G2[((size_t)(b * T_ + t)) * ND_ + nd];
        s += o * sigmoidf_(g);
    }
    out_fp32[i] = s;
    d_out[((size_t)b * CUTS_ + cut_idx) * ND_ + nd] = s;
}

// ======================================================================
extern "C" void kernel_launch(void* const* d_in, const int* in_sizes, int n_in,
                              void* d_out, int out_size, void* d_ws, size_t ws_size,
                              hipStream_t stream)
{
    const float* x        = (const float*)d_in[0];
    const float* h_time   = (const float*)d_in[1];
    const float* h_space  = (const float*)d_in[2];
    const float* gen_Tt_w = (const float*)d_in[3];
    const float* gen_Tt_b = (const float*)d_in[4];
    const float* wg_w1    = (const float*)d_in[5];
    const float* wg_b1    = (const float*)d_in[6];
    const float* wg_w2    = (const float*)d_in[7];
    const float* wg_b2    = (const float*)d_in[8];
    const float* wg_w3    = (const float*)d_in[9];
    const float* wg_b3    = (const float*)d_in[10];
    const float* bg_w1    = (const float*)d_in[11];
    const float* bg_b1    = (const float*)d_in[12];
    const float* bg_w2    = (const float*)d_in[13];
    const float* bg_b2    = (const float*)d_in[14];
    const float* bg_w3    = (const float*)d_in[15];
    const float* bg_b3    = (const float*)d_in[16];
    const float* proxies  = (const float*)d_in[17];
    const float* ta_p1_w  = (const float*)d_in[18];
    const float* ta_p1_b  = (const float*)d_in[19];
    const float* ta_p2_w  = (const float*)d_in[20];
    const float* ta_p2_b  = (const float*)d_in[21];
    const float* rate     = (const float*)d_in[22];
    const float* sa_p1_w  = (const float*)d_in[23];
    const float* sa_p1_b  = (const float*)d_in[24];
    const float* sa_p2_w  = (const float*)d_in[25];
    const float* sa_p2_b  = (const float*)d_in[26];
    const float* agg_w1   = (const float*)d_in[27];
    const float* agg_b1   = (const float*)d_in[28];
    const float* agg_w2   = (const float*)d_in[29];
    const float* agg_b2   = (const float*)d_in[30];

    float* outp = (float*)d_out;

    float* ws = (float*)d_ws;
    const size_t S = (size_t)B_ * TND_;             // 1,378,944 floats
    const size_t genW = (size_t)B_ * T_ * 4096;
    const size_t genB = (size_t)B_ * T_ * 64;
    size_t off = 0;
    float* Wg   = ws + off; off += 4 * genW;
    float* Bg   = ws + off; off += 4 * genB;
    float* A    = ws + off; off += S;
    float* Bb   = ws + off; off += S;
    float* C    = ws + off; off += S;
    float* Dd   = ws + off; off += S;
    float* out_fp32 = ws + off; off += (size_t)B_ * ND_;
    float* Coef = ws + off; off += GBT_ * 16;

    zero_kernel<<<(B_ * ND_ + 255) / 256, 256, 0, stream>>>(out_fp32, B_ * ND_);

    // param_gen: coef stage (416 blocks x 64) + flat materialization
    param_coef_kernel<<<GBT_, 64, 0, stream>>>(
        h_time, h_space, gen_Tt_w, gen_Tt_b,
        wg_w1, wg_b1, wg_w2, wg_b2,
        bg_w1, bg_b1, bg_w2, bg_b2, Coef);
    param_mat_kernel<<<(WTOT + BTOT + 255) / 256, 256, 0, stream>>>(
        wg_w3, wg_b3, bg_w3, bg_b3, Coef, Wg, Bg);

    const int cut_starts[4] = {0, 12, 24, 36};
    const dim3 lcGrid(B_ * T_, NCHUNK, 2);
    const int d2Grid = (M_ + 3) / 4;     // 5382
    const int taGrid = (B_ * N_ * KH * T_ + 255) / 256;

    for (int cut = 0; cut < CUTS_; ++cut) {
        // temporal k (gen0) -> A, v (gen1) -> Bb, from virtual t1
        lincustom_t1_kernel<<<lcGrid, 256, 0, stream>>>(
            x, proxies, out_fp32,
            Wg + 0 * genW, Bg + 0 * genB, Wg + 1 * genW, Bg + 1 * genB,
            A, Bb, cut_starts[cut], cut);
        // temporal attention -> C
        temporal_att_kernel<<<taGrid, 256, 0, stream>>>(
            proxies, out_fp32, A, Bb, rate, C, cut);
        // y = dense(tanh(dense(xatt, p1)), p2) -> Dd
        dense2_kernel<2><<<d2Grid, 256, 0, stream>>>(C, ta_p1_w, ta_p1_b, ta_p2_w, ta_p2_b, Dd, M_);
        // spatial k (gen2) -> A, v (gen3) -> Bb
        lincustom_kernel<<<lcGrid, 256, 0, stream>>>(
            Dd, Wg + 2 * genW, Bg + 2 * genB, Wg + 3 * genW, Bg + 3 * genB, A, Bb);
        // spatial attention (q = Dd) -> C
        spatial_att_kernel<<<B_ * T_ * KH, 256, 0, stream>>>(Dd, A, Bb, C);
        // o = dense(relu(dense(sa_out, p1)), p2) -> Bb
        dense2_kernel<1><<<d2Grid, 256, 0, stream>>>(C, sa_p1_w, sa_p1_b, sa_p2_w, sa_p2_b, Bb, M_);
        // gate pre-sigmoid = dense(relu(dense(o, w1)), w2) -> Dd
        dense2_kernel<1><<<d2Grid, 256, 0, stream>>>(Bb, agg_w1, agg_b1, agg_w2, agg_b2, Dd, M_);
        // out = sum_t o * sigmoid(gate)
        gate_reduce_kernel<<<(B_ * ND_ + 255) / 256, 256, 0, stream>>>(
            Bb, Dd, out_fp32, outp, cut);
    }
}

// Round 9
// 914.706 us; speedup vs baseline: 2.1172x; 2.0026x over previous
//
#include <hip/hip_runtime.h>
#include <hip/hip_bf16.h>

#define B_ 8
#define L_ 48
#define N_ 207
#define D_ 64
#define KH 8
#define T_ 13          // CP = CUT_SIZE + NO_PROXIES
#define CUTS_ 4
#define ND_ (N_ * D_)        // 13248
#define TND_ (T_ * ND_)      // 172224
#define M_ (B_ * T_ * N_)    // 21528 rows for dense layers
#define GBT_ (4 * B_ * T_)   // 416 generator instances

__device__ __forceinline__ float sigmoidf_(float x) { return 1.f / (1.f + expf(-x)); }

__global__ void zero_kernel(float* p, int n) {
    int i = blockIdx.x * blockDim.x + threadIdx.x;
    if (i < n) p[i] = 0.f;
}

// ------------------------------------------------- param_gen stage 1: coefs
__global__ void param_coef_kernel(
    const float* __restrict__ h_time, const float* __restrict__ h_space,
    const float* __restrict__ Ttw, const float* __restrict__ Ttb,
    const float* __restrict__ wg_w1, const float* __restrict__ wg_b1,
    const float* __restrict__ wg_w2, const float* __restrict__ wg_b2,
    const float* __restrict__ bg_w1, const float* __restrict__ bg_b1,
    const float* __restrict__ bg_w2, const float* __restrict__ bg_b2,
    float* __restrict__ Coef)
{
    int blk = blockIdx.x;                 // g*(B*T) + b*T + c
    int g = blk / (B_ * T_);
    int rem = blk % (B_ * T_);
    int b = rem / T_, c = rem % T_;
    const float* h = (g < 2) ? h_time : h_space;
    int lane = threadIdx.x;

    __shared__ float mem2[64];
    __shared__ float m1s[64];

    {
        float s = 0.f;
        for (int l = 0; l < L_; ++l)
            s += tanhf(h[(b * L_ + l) * 64 + lane]) * Ttw[(g * T_ + c) * L_ + l];
        mem2[lane] = tanhf(s + Ttb[g * T_ + c]);
    }
    __syncthreads();
    {
        int j = lane & 31;
        bool isW = lane < 32;
        const float* w1 = isW ? wg_w1 : bg_w1;
        const float* b1 = isW ? wg_b1 : bg_b1;
        float s = b1[g * 32 + j];
        #pragma unroll 8
        for (int hh = 0; hh < 64; ++hh) s += mem2[hh] * w1[(g * 32 + j) * 64 + hh];
        m1s[lane] = fmaxf(s, 0.f);
    }
    __syncthreads();
    if (lane < 5 || (lane >= 8 && lane < 13)) {
        bool isW = lane < 5;
        int j = isW ? lane : lane - 8;
        const float* w2 = isW ? wg_w2 : bg_w2;
        const float* b2 = isW ? wg_b2 : bg_b2;
        int base = isW ? 0 : 32;
        float s = b2[g * 5 + j];
        #pragma unroll
        for (int k = 0; k < 32; ++k) s += m1s[base + k] * w2[(g * 5 + j) * 32 + k];
        Coef[blk * 16 + (isW ? j : 8 + j)] = fmaxf(s, 0.f);
    }
}

// ------------------------------------- param_gen stage 2: materialize W / B
#define WTOT (GBT_ * 4096)      // 1,703,936
#define BTOT (GBT_ * 64)        // 26,624
__global__ void param_mat_kernel(
    const float* __restrict__ wg_w3, const float* __restrict__ wg_b3,
    const float* __restrict__ bg_w3, const float* __restrict__ bg_b3,
    const float* __restrict__ Coef,
    float* __restrict__ Wg, float* __restrict__ Bg)
{
    int i = blockIdx.x * blockDim.x + threadIdx.x;
    if (i < WTOT) {
        int idx = i & 4095;              // = d*64+e
        int blk = i >> 12;
        int g = blk / (B_ * T_);
        const float* w3 = &wg_w3[((size_t)g * 4096 + idx) * 5];
        const float* cf = &Coef[blk * 16];
        Wg[i] = wg_b3[g * 4096 + idx]
              + cf[0]*w3[0] + cf[1]*w3[1] + cf[2]*w3[2] + cf[3]*w3[3] + cf[4]*w3[4];
    } else if (i < WTOT + BTOT) {
        int k = i - WTOT;
        int idx = k & 63;
        int blk = k >> 6;
        int g = blk / (B_ * T_);
        const float* w3 = &bg_w3[((size_t)g * 64 + idx) * 5];
        const float* cf = &Coef[blk * 16];
        Bg[k] = bg_b3[g * 64 + idx]
              + cf[8]*w3[0] + cf[9]*w3[1] + cf[10]*w3[2] + cf[11]*w3[3] + cf[12]*w3[4];
    }
}

// ----------------------------------------------- custom linear (widened)
#define NCHUNK 8
#define NROWS 26   // ceil(207/8)
__global__ void lincustom_t1_kernel(
    const float* __restrict__ x, const float* __restrict__ proxies,
    const float* __restrict__ out_prev,
    const float* __restrict__ W0, const float* __restrict__ Bi0,
    const float* __restrict__ W1, const float* __restrict__ Bi1,
    float* __restrict__ Y0, float* __restrict__ Y1, int cut_start, int cut_idx)
{
    int bt = blockIdx.x;  // b*T + t
    int b = bt / T_, t = bt % T_;
    int which = blockIdx.z;
    const float* W  = which ? W1 : W0;
    const float* Bi = which ? Bi1 : Bi0;
    float* Y        = which ? Y1 : Y0;

    __shared__ float w[4096], bb[64];
    int tid = threadIdx.x;
    for (int i = tid; i < 4096; i += blockDim.x)
        w[i] = W[(size_t)bt * 4096 + i];
    if (tid < 64) bb[tid] = Bi[bt * 64 + tid];
    __syncthreads();

    int n0 = blockIdx.y * NROWS;
    int n1 = min(n0 + NROWS, N_);
    const float* xrow_base = (t > 0) ? (x + ((size_t)(b * L_ + cut_start + t - 1) * N_) * D_) : nullptr;
    for (int ne = n0 * 64 + tid; ne < n1 * 64; ne += blockDim.x) {
        int n = ne >> 6, e = ne & 63;
        float s = bb[e];
        if (t == 0) {
            const float* pp = proxies + (size_t)cut_idx * ND_ + n * 64;
            const float* op = out_prev + (size_t)b * ND_ + n * 64;
            #pragma unroll 8
            for (int d = 0; d < 64; ++d) s += (pp[d] + op[d]) * w[d * 64 + e];
        } else {
            const float* xr = xrow_base + (size_t)n * 64;
            #pragma unroll 8
            for (int d = 0; d < 64; ++d) s += xr[d] * w[d * 64 + e];
        }
        Y[(size_t)bt * ND_ + ne] = s;
    }
}

__global__ void lincustom_kernel(
    const float* __restrict__ X,
    const float* __restrict__ W0, const float* __restrict__ Bi0,
    const float* __restrict__ W1, const float* __restrict__ Bi1,
    float* __restrict__ Y0, float* __restrict__ Y1)
{
    int bt = blockIdx.x;
    int which = blockIdx.z;
    const float* W  = which ? W1 : W0;
    const float* Bi = which ? Bi1 : Bi0;
    float* Y        = which ? Y1 : Y0;

    __shared__ float w[4096], bb[64];
    int tid = threadIdx.x;
    for (int i = tid; i < 4096; i += blockDim.x)
        w[i] = W[(size_t)bt * 4096 + i];
    if (tid < 64) bb[tid] = Bi[bt * 64 + tid];
    __syncthreads();

    int n0 = blockIdx.y * NROWS;
    int n1 = min(n0 + NROWS, N_);
    const float* Xbt = X + (size_t)bt * ND_;
    for (int ne = n0 * 64 + tid; ne < n1 * 64; ne += blockDim.x) {
        int n = ne >> 6, e = ne & 63;
        const float* xr = Xbt + (size_t)n * 64;
        float s = bb[e];
        #pragma unroll 8
        for (int d = 0; d < 64; ++d) s += xr[d] * w[d * 64 + e];
        Y[(size_t)bt * ND_ + ne] = s;
    }
}

// ------------------------------------------------------- temporal attention
__global__ void temporal_att_kernel(
    const float* __restrict__ proxies, const float* __restrict__ out_prev,
    const float* __restrict__ klin, const float* __restrict__ vlin,
    const float* __restrict__ rate, float* __restrict__ xatt, int cut_idx)
{
    int i = blockIdx.x * blockDim.x + threadIdx.x;
    if (i >= B_ * N_ * KH * T_) return;
    int r = i % T_;
    int h = (i / T_) % KH;
    int n = (i / (T_ * KH)) % N_;
    int b = i / (T_ * KH * N_);

    float srate = sigmoidf_(rate[0]);
    const float rs8 = 0.35355339059327373f;  // 1/sqrt(8)

    float q[8];
    #pragma unroll
    for (int j = 0; j < 8; ++j)
        q[j] = proxies[(size_t)cut_idx * ND_ + n * 64 + h * 8 + j]
             + out_prev[(size_t)b * ND_ + n * 64 + h * 8 + j];

    float dec = (float)(T_ - r);
    float p[T_], sum = 0.f;
    for (int t = 0; t < T_; ++t) {
        const float* kp = klin + ((size_t)(b * T_ + t)) * ND_ + n * 64 + h * 8;
        float s = 0.f;
        #pragma unroll
        for (int j = 0; j < 8; ++j) s += q[j] * kp[j];
        float sa = sigmoidf_(s * rs8);
        float sg = sigmoidf_(sa * srate * dec);
        float at = tanhf(sa / (1.f + sg));
        p[t] = expf(at);
        sum += p[t];
    }
    float inv = 1.f / sum;
    float acc[8] = {0,0,0,0,0,0,0,0};
    for (int t = 0; t < T_; ++t) {
        float w = p[t] * inv;
        const float* vp = vlin + ((size_t)(b * T_ + t)) * ND_ + n * 64 + h * 8;
        #pragma unroll
        for (int j = 0; j < 8; ++j) acc[j] += w * vp[j];
    }
    float* op = xatt + ((size_t)(b * T_ + r)) * ND_ + n * 64 + h * 8;
    #pragma unroll
    for (int j = 0; j < 8; ++j) op[j] = acc[j];
}

// ------------------------------------------------------ fused dense-dense
// 32 rows/block; weights transposed+padded in LDS (bank-conflict-free);
// rows staged coalesced; both layers computed from LDS.
template <int ACT1>
__global__ void dense2_kernel(const float* __restrict__ X,
                              const float* __restrict__ W1, const float* __restrict__ b1,
                              const float* __restrict__ W2, const float* __restrict__ b2,
                              float* __restrict__ Y, int M)
{
    __shared__ float w1[64 * 65], w2[64 * 65];   // w[d*65+e] = W[e*64+d]
    __shared__ float bb1[64], bb2[64];
    __shared__ float xs[32][64];
    __shared__ float in2[32][64];
    int tid = threadIdx.x;
    for (int i = tid; i < 4096; i += 256) {
        int e = i >> 6, d = i & 63;
        w1[d * 65 + e] = W1[i];    // lanes: d varies, bank (d*65+e)%32=(d+e)%32 -> conflict-free
        w2[d * 65 + e] = W2[i];
    }
    if (tid < 64) { bb1[tid] = b1[tid]; bb2[tid] = b2[tid]; }
    int row0 = blockIdx.x * 32;
    for (int i = tid; i < 2048; i += 256) {
        int r = i >> 6, d = i & 63;
        int row = row0 + r;
        xs[r][d] = (row < M) ? X[(size_t)row * 64 + d] : 0.f;
    }
    __syncthreads();

    int e = tid & 63;
    int rloc0 = tid >> 6;   // wave id 0..3
    for (int r = rloc0; r < 32; r += 4) {
        float s = bb1[e];
        #pragma unroll 16
        for (int d = 0; d < 64; ++d) s += xs[r][d] * w1[d * 65 + e];
        if (ACT1 == 1) s = fmaxf(s, 0.f);
        else if (ACT1 == 2) s = tanhf(s);
        in2[r][e] = s;
    }
    __syncthreads();
    for (int r = rloc0; r < 32; r += 4) {
        int row = row0 + r;
        if (row >= M) break;
        float o = bb2[e];
        #pragma unroll 16
        for (int d = 0; d < 64; ++d) o += in2[r][d] * w2[d * 65 + e];
        Y[(size_t)row * 64 + e] = o;
    }
}

// -------------------------------------------------------- spatial attention
// Online softmax: single pass over keys.
__global__ void spatial_att_kernel(const float* __restrict__ Yq,
                                   const float* __restrict__ Ks, const float* __restrict__ Vs,
                                   float* __restrict__ Out)
{
    int blk = blockIdx.x;  // (b*T + t)*KH + h
    int h = blk % KH;
    int bt = blk / KH;
    __shared__ float kl[N_ * 8], vl[N_ * 8];
    int tid = threadIdx.x;
    for (int i = tid; i < N_ * 8; i += blockDim.x) {
        int m = i / 8, j = i % 8;
        kl[i] = Ks[(size_t)bt * ND_ + m * 64 + h * 8 + j];
        vl[i] = Vs[(size_t)bt * ND_ + m * 64 + h * 8 + j];
    }
    __syncthreads();
    const float rs8 = 0.35355339059327373f;
    for (int n = tid; n < N_; n += blockDim.x) {
        float q[8];
        const float* qp = Yq + (size_t)bt * ND_ + n * 64 + h * 8;
        #pragma unroll
        for (int j = 0; j < 8; ++j) q[j] = qp[j] * rs8;
        float mx = -3.4e38f, sum = 0.f;
        float acc[8] = {0,0,0,0,0,0,0,0};
        for (int m = 0; m < N_; ++m) {
            float s = 0.f;
            #pragma unroll
            for (int j = 0; j < 8; ++j) s += q[j] * kl[m * 8 + j];
            if (s > mx) {
                float c = expf(mx - s);
                sum *= c;
                #pragma unroll
                for (int j = 0; j < 8; ++j) acc[j] *= c;
                mx = s;
            }
            float p = expf(s - mx);
            sum += p;
            #pragma unroll
            for (int j = 0; j < 8; ++j) acc[j] += p * vl[m * 8 + j];
        }
        float inv = 1.f / sum;
        float* op = Out + (size_t)bt * ND_ + n * 64 + h * 8;
        #pragma unroll
        for (int j = 0; j < 8; ++j) op[j] = acc[j] * inv;
    }
}

// ------------------------------------------------------------- gate + reduce
__global__ void gate_reduce_kernel(const float* __restrict__ O, const float* __restrict__ G2,
                                   float* __restrict__ out_fp32, float* __restrict__ d_out,
                                   int cut_idx)
{
    int i = blockIdx.x * blockDim.x + threadIdx.x;
    if (i >= B_ * ND_) return;
    int b = i / ND_;
    int nd = i % ND_;
    float s = 0.f;
    for (int t = 0; t < T_; ++t) {
        float o = O[((size_t)(b * T_ + t)) * ND_ + nd];
        float g = G2[((size_t)(b * T_ + t)) * ND_ + nd];
        s += o * sigmoidf_(g);
    }
    out_fp32[i] = s;
    d_out[((size_t)b * CUTS_ + cut_idx) * ND_ + nd] = s;
}

// ======================================================================
extern "C" void kernel_launch(void* const* d_in, const int* in_sizes, int n_in,
                              void* d_out, int out_size, void* d_ws, size_t ws_size,
                              hipStream_t stream)
{
    const float* x        = (const float*)d_in[0];
    const float* h_time   = (const float*)d_in[1];
    const float* h_space  = (const float*)d_in[2];
    const float* gen_Tt_w = (const float*)d_in[3];
    const float* gen_Tt_b = (const float*)d_in[4];
    const float* wg_w1    = (const float*)d_in[5];
    const float* wg_b1    = (const float*)d_in[6];
    const float* wg_w2    = (const float*)d_in[7];
    const float* wg_b2    = (const float*)d_in[8];
    const float* wg_w3    = (const float*)d_in[9];
    const float* wg_b3    = (const float*)d_in[10];
    const float* bg_w1    = (const float*)d_in[11];
    const float* bg_b1    = (const float*)d_in[12];
    const float* bg_w2    = (const float*)d_in[13];
    const float* bg_b2    = (const float*)d_in[14];
    const float* bg_w3    = (const float*)d_in[15];
    const float* bg_b3    = (const float*)d_in[16];
    const float* proxies  = (const float*)d_in[17];
    const float* ta_p1_w  = (const float*)d_in[18];
    const float* ta_p1_b  = (const float*)d_in[19];
    const float* ta_p2_w  = (const float*)d_in[20];
    const float* ta_p2_b  = (const float*)d_in[21];
    const float* rate     = (const float*)d_in[22];
    const float* sa_p1_w  = (const float*)d_in[23];
    const float* sa_p1_b  = (const float*)d_in[24];
    const float* sa_p2_w  = (const float*)d_in[25];
    const float* sa_p2_b  = (const float*)d_in[26];
    const float* agg_w1   = (const float*)d_in[27];
    const float* agg_b1   = (const float*)d_in[28];
    const float* agg_w2   = (const float*)d_in[29];
    const float* agg_b2   = (const float*)d_in[30];

    float* outp = (float*)d_out;

    float* ws = (float*)d_ws;
    const size_t S = (size_t)B_ * TND_;             // 1,378,944 floats
    const size_t genW = (size_t)B_ * T_ * 4096;
    const size_t genB = (size_t)B_ * T_ * 64;
    size_t off = 0;
    float* Wg   = ws + off; off += 4 * genW;
    float* Bg   = ws + off; off += 4 * genB;
    float* A    = ws + off; off += S;
    float* Bb   = ws + off; off += S;
    float* C    = ws + off; off += S;
    float* Dd   = ws + off; off += S;
    float* out_fp32 = ws + off; off += (size_t)B_ * ND_;
    float* Coef = ws + off; off += GBT_ * 16;

    zero_kernel<<<(B_ * ND_ + 255) / 256, 256, 0, stream>>>(out_fp32, B_ * ND_);

    param_coef_kernel<<<GBT_, 64, 0, stream>>>(
        h_time, h_space, gen_Tt_w, gen_Tt_b,
        wg_w1, wg_b1, wg_w2, wg_b2,
        bg_w1, bg_b1, bg_w2, bg_b2, Coef);
    param_mat_kernel<<<(WTOT + BTOT + 255) / 256, 256, 0, stream>>>(
        wg_w3, wg_b3, bg_w3, bg_b3, Coef, Wg, Bg);

    const int cut_starts[4] = {0, 12, 24, 36};
    const dim3 lcGrid(B_ * T_, NCHUNK, 2);
    const int d2Grid = (M_ + 31) / 32;   // 673
    const int taGrid = (B_ * N_ * KH * T_ + 255) / 256;

    for (int cut = 0; cut < CUTS_; ++cut) {
        // temporal k (gen0) -> A, v (gen1) -> Bb, from virtual t1
        lincustom_t1_kernel<<<lcGrid, 256, 0, stream>>>(
            x, proxies, out_fp32,
            Wg + 0 * genW, Bg + 0 * genB, Wg + 1 * genW, Bg + 1 * genB,
            A, Bb, cut_starts[cut], cut);
        // temporal attention -> C
        temporal_att_kernel<<<taGrid, 256, 0, stream>>>(
            proxies, out_fp32, A, Bb, rate, C, cut);
        // y = dense(tanh(dense(xatt, p1)), p2) -> Dd
        dense2_kernel<2><<<d2Grid, 256, 0, stream>>>(C, ta_p1_w, ta_p1_b, ta_p2_w, ta_p2_b, Dd, M_);
        // spatial k (gen2) -> A, v (gen3) -> Bb
        lincustom_kernel<<<lcGrid, 256, 0, stream>>>(
            Dd, Wg + 2 * genW, Bg + 2 * genB, Wg + 3 * genW, Bg + 3 * genB, A, Bb);
        // spatial attention (q = Dd) -> C
        spatial_att_kernel<<<B_ * T_ * KH, 256, 0, stream>>>(Dd, A, Bb, C);
        // o = dense(relu(dense(sa_out, p1)), p2) -> Bb
        dense2_kernel<1><<<d2Grid, 256, 0, stream>>>(C, sa_p1_w, sa_p1_b, sa_p2_w, sa_p2_b, Bb, M_);
        // gate pre-sigmoid = dense(relu(dense(o, w1)), w2) -> Dd
        dense2_kernel<1><<<d2Grid, 256, 0, stream>>>(Bb, agg_w1, agg_b1, agg_w2, agg_b2, Dd, M_);
        // out = sum_t o * sigmoid(gate)
        gate_reduce_kernel<<<(B_ * ND_ + 255) / 256, 256, 0, stream>>>(
            Bb, Dd, out_fp32, outp, cut);
    }
}